// Round 22
// baseline (175.787 us; speedup 1.0000x reference)
//
#include <hip/hip_runtime.h>
#include <stdint.h>

// ---------------- types & helpers ----------------
typedef __bf16   bf16x8 __attribute__((ext_vector_type(8)));
typedef float    f32x4  __attribute__((ext_vector_type(4)));
typedef float    f32x16 __attribute__((ext_vector_type(16)));
typedef uint16_t u16x8  __attribute__((ext_vector_type(8)));
typedef uint16_t u16x4  __attribute__((ext_vector_type(4)));
typedef uint32_t u32x4  __attribute__((ext_vector_type(4)));

#define DEVFN static __device__ __forceinline__

DEVFN uint16_t f2bf(float f){            // RNE f32 -> bf16
  uint32_t u = __builtin_bit_cast(uint32_t, f);
  u += 0x7fffu + ((u >> 16) & 1u);
  return (uint16_t)(u >> 16);
}
DEVFN float bf2f(uint16_t h){
  return __builtin_bit_cast(float, (uint32_t)h << 16);
}
DEVFN bf16x8 ldbf8(const uint16_t* p){
  return __builtin_bit_cast(bf16x8, *(const u16x8*)p);
}
DEVFN void gl16(const void* g, void* l){ // async global->LDS, 16B/lane, LDS base wave-uniform
  __builtin_amdgcn_global_load_lds((__attribute__((address_space(1))) void*)g,
                                   (__attribute__((address_space(3))) void*)l,
                                   16, 0, 0);
}
DEVFN f32x4 mfma16(bf16x8 a, bf16x8 b, f32x4 c){
  return __builtin_amdgcn_mfma_f32_16x16x32_bf16(a, b, c, 0, 0, 0);
}
DEVFN f32x16 mfma32(bf16x8 a, bf16x8 b, f32x16 c){
  return __builtin_amdgcn_mfma_f32_32x32x16_bf16(a, b, c, 0, 0, 0);
}
DEVFN uint32_t cvtpk(float lo, float hi){          // pack 2 f32 -> 2 bf16 in one dword
  uint32_t r;
  asm("v_cvt_pk_bf16_f32 %0, %1, %2" : "=v"(r) : "v"(lo), "v"(hi));
  return r;
}
DEVFN void plswap(uint32_t &x, uint32_t &y){       // swap x.hi-lanes <-> y.lo-lanes
  asm("v_permlane32_swap_b32 %0, %1" : "+v"(x), "+v"(y));
}
// head-local column permutation: rope pair (j, j+128) -> (p, p+16)
DEVFN int permcol(int j){
  return (((j & 127) >> 4) << 5) + (((j >> 7) & 1) << 4) + (j & 15);
}
// fast sincos via HW v_sin/v_cos (input in REVOLUTIONS; fract -> valid domain).
DEVFN void fastsc(float rad, float& sn, float& cs){
  float rev = rad * 0.15915494309189535f;
  rev = __builtin_amdgcn_fractf(rev);
  sn = __builtin_amdgcn_sinf(rev);
  cs = __builtin_amdgcn_cosf(rev);
}

// ---------------- fused pre-pass: RMSNorm + weight transpose + mask detect ----------------
// blocks 0..20479: rmsnorm rows; 20480..27647: transpose tiles; 27648..27663: mask detect.
__global__ __launch_bounds__(256) void fused_pre_k(const float* __restrict__ x,
                                                   const float* __restrict__ mem,
                                                   uint16_t* __restrict__ xn,
                                                   uint16_t* __restrict__ mn,
                                                   const float* __restrict__ scale,
                                                   const float* __restrict__ qw,
                                                   const float* __restrict__ kvw,
                                                   const float* __restrict__ ow,
                                                   uint16_t* __restrict__ wq,
                                                   uint16_t* __restrict__ wkv,
                                                   uint16_t* __restrict__ wout,
                                                   const uint32_t* __restrict__ mask32,
                                                   int* __restrict__ flag){
  int bid = blockIdx.x;
  if (bid < 20480){
    int row = bid;                 // first 4096 -> x, rest -> mem
    const float* in; uint16_t* out; int r0;
    if (row < 4096){ in = x;  out = xn; r0 = row; }
    else           { in = mem; out = mn; r0 = row - 4096; }
    const float4* ip = (const float4*)(in + (size_t)r0 * 1024);
    float4 v = ip[threadIdx.x];
    float ss = v.x*v.x + v.y*v.y + v.z*v.z + v.w*v.w;
    #pragma unroll
    for (int off = 1; off < 64; off <<= 1) ss += __shfl_xor(ss, off);
    __shared__ float wsum[4];
    if ((threadIdx.x & 63) == 0) wsum[threadIdx.x >> 6] = ss;
    __syncthreads();
    float r = rsqrtf((wsum[0] + wsum[1] + wsum[2] + wsum[3]) * (1.0f/1024.0f) + 1e-6f);
    float4 sc = ((const float4*)scale)[threadIdx.x];
    u16x4 o;
    o[0] = f2bf(v.x * r * (1.0f + sc.x));
    o[1] = f2bf(v.y * r * (1.0f + sc.y));
    o[2] = f2bf(v.z * r * (1.0f + sc.z));
    o[3] = f2bf(v.w * r * (1.0f + sc.w));
    *(u16x4*)(out + (size_t)r0 * 1024 + threadIdx.x * 4) = o;
  } else if (bid < 27648){
    int t = bid - 20480;           // 7168 = z(7) x y(32) x x(32)
    int z = t >> 10, rem = t & 1023;
    int r0 = (rem >> 5) * 32, c0 = (rem & 31) * 32;
    const float* in; uint16_t* out; int rs, C;
    bool perm;
    if (z < 4)      { in = qw  + z*262144;     out = wq  + z*262144;     rs = 256;  C = 256;  perm = true;  }
    else if (z < 6) { in = kvw + (z-4)*262144; out = wkv + (z-4)*262144; rs = 256;  C = 256;  perm = (z == 4); }
    else            { in = ow;                 out = wout;               rs = 1024; C = 1024; perm = false; }
    if (c0 >= C) return;
    __shared__ float tt[32][33];
    int tx = threadIdx.x & 31, ty = threadIdx.x >> 5;   // (32,8)
    #pragma unroll
    for (int i = 0; i < 4; ++i)
      tt[ty + 8*i][tx] = in[(size_t)(r0 + ty + 8*i) * rs + c0 + tx];
    __syncthreads();
    #pragma unroll
    for (int i = 0; i < 4; ++i){
      int c = c0 + ty + 8*i;
      int pc = perm ? permcol(c) : c;
      out[(size_t)pc * 1024 + r0 + tx] = f2bf(tt[tx][ty + 8*i]);
    }
  } else {
    int i = (bid - 27648) * 256 + threadIdx.x;       // 4096 dwords (16KB, dtype-safe)
    uint32_t v = mask32[i];
    int notint   = (v > 1u) ? 1 : 0;
    int notfloat = (v != 0u && v != 0x3F800000u) ? 2 : 0;
    int bits = notint | notfloat;
    if (__any(bits)){
      int agg = bits;
      agg |= __shfl_xor(agg, 1);  agg |= __shfl_xor(agg, 2);
      agg |= __shfl_xor(agg, 4);  agg |= __shfl_xor(agg, 8);
      agg |= __shfl_xor(agg, 16); agg |= __shfl_xor(agg, 32);
      if ((threadIdx.x & 63) == 0) atomicOr(flag, agg);
    }
  }
}

// ---------------- shared GEMM body: BK=64, XOR-swizzled LDS (r18 measured-best) ----------------
#define GEMM_BODY(A_, Bt_, K_)                                                  \
  __shared__ __align__(16) uint16_t As[128*64];                                 \
  __shared__ __align__(16) uint16_t Bs[128*64];                                 \
  f32x4 acc[4][4] = {};                                                         \
  {                                                                             \
    const int K = (K_);                                                         \
    _Pragma("unroll 1")                                                         \
    for (int k0 = 0; k0 < K; k0 += 64){                                         \
      __syncthreads();                                                          \
      _Pragma("unroll")                                                         \
      for (int it = 0; it < 4; ++it){                                           \
        int ob = it * 4096 + tid * 16;                                          \
        int row = ob >> 7;                                                      \
        int col = (ob & 127) ^ ((row & 7) << 4);                                \
        gl16((const char*)(A_)  + ((size_t)(m0 + row) * K + k0) * 2 + col,      \
             (char*)As + it * 4096 + wid * 1024);                               \
        gl16((const char*)(Bt_) + ((size_t)(n0 + row) * K + k0) * 2 + col,      \
             (char*)Bs + it * 4096 + wid * 1024);                               \
      }                                                                         \
      __syncthreads();                                                          \
      bf16x8 af[2][4], bfr[2][4];                                               \
      _Pragma("unroll")                                                         \
      for (int ks = 0; ks < 2; ++ks){                                           \
        _Pragma("unroll")                                                       \
        for (int m = 0; m < 4; ++m)                                             \
          af[ks][m]  = ldbf8(&As[(wr*64 + m*16 + lr) * 64 +                     \
                                 ((ks*32 + lq*8) ^ ((lr & 7) << 3))]);          \
        _Pragma("unroll")                                                       \
        for (int n = 0; n < 4; ++n)                                             \
          bfr[ks][n] = ldbf8(&Bs[(wc*64 + n*16 + lr) * 64 +                     \
                                 ((ks*32 + lq*8) ^ ((lr & 7) << 3))]);          \
      }                                                                         \
      _Pragma("unroll")                                                         \
      for (int ks = 0; ks < 2; ++ks)                                            \
        _Pragma("unroll")                                                       \
        for (int m = 0; m < 4; ++m)                                             \
          _Pragma("unroll")                                                     \
          for (int n = 0; n < 4; ++n)                                           \
            acc[m][n] = mfma16(af[ks][m], bfr[ks][n], acc[m][n]);               \
    }                                                                           \
  }

// ---------------- fused q+kv GEMM; RoPE (HW sin/cos) fused; XCD A-panel affinity ----------------
__global__ __launch_bounds__(256) void gemm_qkv_k(const uint16_t* __restrict__ xn,
                                                  const uint16_t* __restrict__ mn,
                                                  const uint16_t* __restrict__ wq,
                                                  const uint16_t* __restrict__ wkv,
                                                  uint16_t* __restrict__ qb,
                                                  uint16_t* __restrict__ kb,
                                                  uint16_t* __restrict__ vt3){
  int bx = blockIdx.x;
  bool isq = bx < 256;
  const uint16_t *A, *Bt;
  int n0, m0;
  if (isq){
    int m = (bx & 7) + 8 * (bx >> 6);      // XCD = bx%8 = m%8: A-panel pinned to one XCD
    int n = (bx >> 3) & 7;
    A = xn; Bt = wq;  n0 = n * 128;  m0 = m * 128;
  } else {
    int b2 = bx - 256;
    int m = (b2 & 7) + 8 * (b2 >> 5);      // same affinity for kv (256%8==0 preserves xcd)
    int n = (b2 >> 3) & 3;
    A = mn; Bt = wkv; n0 = n * 128; m0 = m * 128;
  }
  int tid = threadIdx.x, lane = tid & 63, wid = tid >> 6;
  int wr = wid >> 1, wc = wid & 1;
  int lr = lane & 15, lq = lane >> 4;
  GEMM_BODY(A, Bt, 1024)
  if (isq){
    // q-block: RoPE fused; v_sin/v_cos path
    #pragma unroll
    for (int m = 0; m < 4; ++m){
      int gr0 = m0 + wr*64 + m*16 + lq*4;
      #pragma unroll
      for (int np = 0; np < 2; ++np){
        int gcl = n0 + wc*64 + (2*np)*16 + lr;         // bit4 == 0: first-half col
        int j = (((gcl & 255) >> 5) << 4) + (gcl & 15);
        float inv = exp2f((float)j * (-13.287712379549449f / 128.0f));
        #pragma unroll
        for (int r = 0; r < 4; ++r){
          float rad = (float)(2048 + ((gr0 + r) & 511)) * inv;
          float sn, cs; fastsc(rad, sn, cs);
          float x1 = acc[m][2*np][r], x2 = acc[m][2*np + 1][r];
          qb[(size_t)(gr0 + r) * 1024 + gcl]      = f2bf((x1*cs - x2*sn) * 0.0625f);
          qb[(size_t)(gr0 + r) * 1024 + gcl + 16] = f2bf((x2*cs + x1*sn) * 0.0625f);
        }
      }
    }
  } else if (n0 < 256){
    // k-block: RoPE fused
    #pragma unroll
    for (int m = 0; m < 4; ++m){
      int gr0 = m0 + wr*64 + m*16 + lq*4;
      #pragma unroll
      for (int np = 0; np < 2; ++np){
        int gcl = n0 + wc*64 + (2*np)*16 + lr;
        int j = ((gcl >> 5) << 4) + (gcl & 15);
        float inv = exp2f((float)j * (-13.287712379549449f / 128.0f));
        #pragma unroll
        for (int r = 0; r < 4; ++r){
          float rad = (float)((gr0 + r) & 2047) * inv;
          float sn, cs; fastsc(rad, sn, cs);
          float x1 = acc[m][2*np][r], x2 = acc[m][2*np + 1][r];
          kb[(size_t)(gr0 + r) * 256 + gcl]      = f2bf(x1*cs - x2*sn);
          kb[(size_t)(gr0 + r) * 256 + gcl + 16] = f2bf(x2*cs + x1*sn);
        }
      }
    }
  } else {
    #pragma unroll
    for (int m = 0; m < 4; ++m)
      #pragma unroll
      for (int n = 0; n < 4; ++n){
        int gr0 = m0 + wr*64 + m*16 + lq*4;
        int gc  = n0 + wc*64 + n*16 + lr;
        int h = gc - 256, bb = gr0 >> 11, s0 = gr0 & 2047;
        int st = s0 >> 5, sc = (s0 >> 3) & 3, s8 = s0 & 7;   // s8 in {0,4}
        u16x4 pk;
        #pragma unroll
        for (int r = 0; r < 4; ++r) pk[r] = f2bf(acc[m][n][r]);
        *(u16x4*)&vt3[((((size_t)bb*64 + st)*4 + sc)*256 + h)*8 + s8] = pk;
      }
  }
}

// ---------------- out GEMM with FUSED 4-way partial merge (r22) ----------------
// A[row][k] = sum_h po_h[row][k] * scale[row][n(k)][h], n(k)=k>>8 (uniform per
// 64-col K-tile). scale precomputed in LDS; A reg-staged + merged + ds_write to
// the SAME swizzled layout (write-side XOR == old source-side XOR; reads unchanged).
// Replaces the standalone merge kernel + enc round-trip.
__global__ __launch_bounds__(256) void gemm_out_k(const uint16_t* __restrict__ po, // [4][4096][1024]
                                                  const float* __restrict__ pm,
                                                  const float* __restrict__ pl,
                                                  const uint16_t* __restrict__ Bt,
                                                  float* __restrict__ Cf){
  int bx = blockIdx.x;                      // 256 blocks, 1-D, XCD A-panel affinity
  int m = (bx & 7) + 8 * (bx >> 6);
  int n = (bx >> 3) & 7;
  int n0 = n * 128, m0 = m * 128;
  int tid = threadIdx.x, lane = tid & 63, wid = tid >> 6;
  int wr = wid >> 1, wc = wid & 1;
  int lr = lane & 15, lq = lane >> 4;
  __shared__ __align__(16) uint16_t As[128*64];
  __shared__ __align__(16) uint16_t Bs[128*64];
  __shared__ float sc_lds[128][4][4];       // [row][head][partial]
  f32x4 acc[4][4] = {};

  // prologue: merge scales, 512 (row, head) entries, 2 per thread
  for (int e = tid; e < 512; e += 256){
    int row = e >> 2, hd = e & 3;
    int gi = (m0 + row) * 4 + hd;
    float pmv[4], plv[4], m4 = -1e30f;
    #pragma unroll
    for (int h = 0; h < 4; ++h){
      pmv[h] = pm[h*16384 + gi];
      plv[h] = pl[h*16384 + gi];
      m4 = fmaxf(m4, pmv[h]);
    }
    float wv[4], ls = 0.0f;
    #pragma unroll
    for (int h = 0; h < 4; ++h){ wv[h] = __expf(pmv[h] - m4); ls += plv[h]*wv[h]; }
    float inv = 1.0f / ls;
    #pragma unroll
    for (int h = 0; h < 4; ++h) sc_lds[row][hd][h] = wv[h] * inv;
  }

  #pragma unroll 1
  for (int k0 = 0; k0 < 1024; k0 += 64){
    __syncthreads();                        // covers sc_lds on first iter; tile reuse after
    int hd = k0 >> 8;
    #pragma unroll
    for (int it = 0; it < 4; ++it){
      int ob = it * 4096 + tid * 16;
      int row = ob >> 7;
      int colb = ob & 127;
      int scolb = colb ^ ((row & 7) << 4);
      gl16((const char*)Bt + ((size_t)(n0 + row) * 1024 + k0) * 2 + scolb,
           (char*)Bs + it * 4096 + wid * 1024);
      size_t abase = ((size_t)(m0 + row) * 1024 + k0) * 2 + colb;   // linear source
      u16x8 pp0 = *(const u16x8*)((const char*)po                    + abase);
      u16x8 pp1 = *(const u16x8*)((const char*)po + (size_t)8388608  + abase);
      u16x8 pp2 = *(const u16x8*)((const char*)po + (size_t)16777216 + abase);
      u16x8 pp3 = *(const u16x8*)((const char*)po + (size_t)25165824 + abase);
      float s0_ = sc_lds[row][hd][0], s1_ = sc_lds[row][hd][1];
      float s2_ = sc_lds[row][hd][2], s3_ = sc_lds[row][hd][3];
      u16x8 mrg;
      #pragma unroll
      for (int e2 = 0; e2 < 8; ++e2){
        float a = bf2f(pp0[e2])*s0_ + bf2f(pp1[e2])*s1_
                + bf2f(pp2[e2])*s2_ + bf2f(pp3[e2])*s3_;
        mrg[e2] = f2bf(a);
      }
      *(u16x8*)((char*)As + row * 128 + scolb) = mrg;   // swizzled LDS write
    }
    __syncthreads();
    bf16x8 af[2][4], bfr[2][4];
    #pragma unroll
    for (int ks = 0; ks < 2; ++ks){
      #pragma unroll
      for (int mm = 0; mm < 4; ++mm)
        af[ks][mm]  = ldbf8(&As[(wr*64 + mm*16 + lr) * 64 + ((ks*32 + lq*8) ^ ((lr & 7) << 3))]);
      #pragma unroll
      for (int nn = 0; nn < 4; ++nn)
        bfr[ks][nn] = ldbf8(&Bs[(wc*64 + nn*16 + lr) * 64 + ((ks*32 + lq*8) ^ ((lr & 7) << 3))]);
    }
    #pragma unroll
    for (int ks = 0; ks < 2; ++ks)
      #pragma unroll
      for (int mm = 0; mm < 4; ++mm)
        #pragma unroll
        for (int nn = 0; nn < 4; ++nn)
          acc[mm][nn] = mfma16(af[ks][mm], bfr[ks][nn], acc[mm][nn]);
  }
  #pragma unroll
  for (int mm = 0; mm < 4; ++mm)
    #pragma unroll
    for (int nn = 0; nn < 4; ++nn){
      int gr0 = m0 + wr*64 + mm*16 + lq*4;
      int gc  = n0 + wc*64 + nn*16 + lr;
      #pragma unroll
      for (int r = 0; r < 4; ++r) Cf[(size_t)(gr0 + r) * 1024 + gc] = acc[mm][nn][r];
    }
}

// ---------------- flash attention: r14 config + direct-mask prologue ----------------
__global__ __launch_bounds__(512, 2) void attn_k(const uint16_t* __restrict__ Q,
                                                 const uint16_t* __restrict__ Kb,
                                                 const uint16_t* __restrict__ Vt3,
                                                 const void* __restrict__ mask,
                                                 const int* __restrict__ flag,
                                                 uint16_t* __restrict__ po,   // [4][4096][1024] bf16
                                                 float* __restrict__ pm,
                                                 float* __restrict__ pl){
  int bx = blockIdx.x;
  int b = bx & 7, qt = (bx >> 3) & 7, sh = bx >> 6;
  int tid = threadIdx.x, lane = tid & 63, wid = tid >> 6;
  int n = wid & 3, qs = wid >> 2;
  int lc = lane & 31, hi = lane >> 5;
  __shared__ __align__(16) uint16_t Ks[3*32*256];   // [buf][s][k], swizzled
  __shared__ __align__(16) uint16_t Vs[3*4*256*8];  // [buf][sc][h][8s] = linear panel copy
  __shared__ uint32_t mask_lds[16];

  int sbeg = sh * 512;
  {
    int f = *flag;                                  // uniform scalar
    int gi = b*2048 + sbeg + tid;
    bool on;
    if ((f & 1) == 0)      on = ((const int*)mask)[gi]    != 0;     // int32
    else if ((f & 2) == 0) on = ((const float*)mask)[gi]  != 0.0f;  // float32
    else                   on = ((const uint8_t*)mask)[gi] != 0;    // bool bytes
    unsigned long long bal = __ballot(on);          // wave wid covers s [wid*64, +64)
    if (lane == 0){
      mask_lds[wid*2]     = (uint32_t)bal;
      mask_lds[wid*2 + 1] = (uint32_t)(bal >> 32);
    }
  }

  int t0w = qt*64 + qs*32;                          // wave's 32 q-rows
  bf16x8 qf[16];
  {
    const uint16_t* qp = Q + (size_t)(b*512 + t0w + lc) * 1024 + n*256 + hi*8;
    #pragma unroll
    for (int kc = 0; kc < 16; ++kc) qf[kc] = ldbf8(qp + kc*16);
  }
  f32x16 o[8] = {};                                 // O[32q][256h]
  float mrow = -1e30f, lrow = 0.0f;

  auto STAGE = [&](int buf, int s0){
    const char* vsrc = (const char*)Vt3 + ((size_t)(b*64 + (s0 >> 5))) * 16384;
    #pragma unroll
    for (int it = 0; it < 2; ++it){
      int ob = it*8192 + tid*16;
      int krow = ob >> 9;                           // K: [32 s][512B], XOR-pre-swizzled source
      int kcol = (ob & 511) ^ ((krow & 7) << 4);
      gl16((const char*)Kb + ((size_t)(b*2048 + s0 + krow) * 256) * 2 + kcol,
           (char*)Ks + buf*16384 + it*8192 + wid*1024);
      gl16(vsrc + ob,                               // V: linear coalesced panel copy
           (char*)Vs + buf*16384 + it*8192 + wid*1024);
    }
  };

  STAGE(0, sbeg);
  STAGE(1, sbeg + 32);

  #pragma unroll 1
  for (int t = 0; t < 16; ++t){
    if (t == 0)      asm volatile("s_waitcnt vmcnt(4) lgkmcnt(0)" ::: "memory");
    else if (t < 15) asm volatile("s_waitcnt vmcnt(4)" ::: "memory");
    else             asm volatile("s_waitcnt vmcnt(0)" ::: "memory");
    __builtin_amdgcn_s_barrier();
    asm volatile("" ::: "memory");
    if (t < 14) STAGE((t+2)%3, sbeg + (t+2)*32);

    const uint16_t* ksb = Ks + (t%3)*8192;
    const uint16_t* vsb = Vs + (t%3)*8192;

    // swapped QK^T: C[s][q], col = q = lc, row s = (reg&3)+8*(reg>>2)+4*hi
    f32x16 sacc = {};
    __builtin_amdgcn_s_setprio(1);
    #pragma unroll
    for (int kc = 0; kc < 16; ++kc){
      bf16x8 ak = ldbf8(&ksb[lc*256 + ((kc*16 + hi*8) ^ ((lc & 7) << 3))]);
      sacc = mfma32(ak, qf[kc], sacc);
    }
    __builtin_amdgcn_s_setprio(0);

    // in-register masked online softmax (lane owns q = lc)
    uint32_t mw = mask_lds[t];
    int sb4 = hi * 4;
    float p[16];
    float mx = -1e30f;
    #pragma unroll
    for (int r = 0; r < 16; ++r){
      int sr = (r & 3) + 8*(r >> 2) + sb4;
      float v = ((mw >> sr) & 1u) ? sacc[r] : -1e30f;
      p[r] = v;
      mx = fmaxf(mx, v);
    }
    mx = fmaxf(mx, __shfl_xor(mx, 32));
    if (__any(mx > mrow + 8.0f)){                   // defer-max (T13)
      float mn2 = fmaxf(mrow, mx);
      float scl = __expf(mrow - mn2);
      mrow = mn2; lrow *= scl;
      #pragma unroll
      for (int ht = 0; ht < 8; ++ht) o[ht] *= scl;
    }
    float rs = 0.0f;
    #pragma unroll
    for (int r = 0; r < 16; ++r){ p[r] = __expf(p[r] - mrow); rs += p[r]; }
    rs += __shfl_xor(rs, 32);
    lrow += rs;

    // P -> bf16 A-frags in registers: cvt_pk pairs + permlane32_swap (T12)
    uint32_t w0, w1, w2, w3, w4, w5, w6, w7;
    w0 = cvtpk(p[0], p[1]);   w2 = cvtpk(p[4], p[5]);   plswap(w0, w2);
    w1 = cvtpk(p[2], p[3]);   w3 = cvtpk(p[6], p[7]);   plswap(w1, w3);
    w4 = cvtpk(p[8], p[9]);   w6 = cvtpk(p[12], p[13]); plswap(w4, w6);
    w5 = cvtpk(p[10], p[11]); w7 = cvtpk(p[14], p[15]); plswap(w5, w7);
    u32x4 t0v = {w0, w1, w2, w3};
    u32x4 t1v = {w4, w5, w6, w7};
    bf16x8 pa0 = __builtin_bit_cast(bf16x8, t0v);   // k = s 0..15
    bf16x8 pa1 = __builtin_bit_cast(bf16x8, t1v);   // k = s 16..31

    // PV: O[q][h], B = V[s][h] from subtiled LDS (conflict-free b128)
    __builtin_amdgcn_s_setprio(1);
    #pragma unroll
    for (int ht = 0; ht < 8; ++ht){
      bf16x8 bv0 = ldbf8(&vsb[(size_t)hi*2048       + (ht*32 + lc)*8]);
      o[ht] = mfma32(pa0, bv0, o[ht]);
      bf16x8 bv1 = ldbf8(&vsb[(size_t)(2 + hi)*2048 + (ht*32 + lc)*8]);
      o[ht] = mfma32(pa1, bv1, o[ht]);
    }
    __builtin_amdgcn_s_setprio(0);
  }

  // epilogue: unscaled partial o (bf16) + per-q m,l
  uint16_t* pop = po + (size_t)sh * 4194304;
  #pragma unroll
  for (int ht = 0; ht < 8; ++ht)
    #pragma unroll
    for (int r = 0; r < 16; ++r){
      int qr = (r & 3) + 8*(r >> 2) + hi*4;
      pop[(size_t)(b*512 + t0w + qr)*1024 + n*256 + ht*32 + lc] = f2bf(o[ht][r]);
    }
  if (hi == 0){
    int mlidx = sh*16384 + (b*512 + t0w + lc)*4 + n;
    pm[mlidx] = mrow;
    pl[mlidx] = lrow;
  }
}

// ---------------- launcher ----------------
extern "C" void kernel_launch(void* const* d_in, const int* in_sizes, int n_in,
                              void* d_out, int out_size, void* d_ws, size_t ws_size,
                              hipStream_t stream){
  const float* x    = (const float*)d_in[0];   // [8][512][1024]
  const float* mem  = (const float*)d_in[1];   // [8][2048][1024]
  const void*  mask = d_in[2];                 // [8][2048]
  const float* rms  = (const float*)d_in[3];   // [1024]
  const float* qw   = (const float*)d_in[4];   // [4][1024][256]
  const float* kvw  = (const float*)d_in[5];   // [2][1][1024][256]
  const float* ow   = (const float*)d_in[6];   // [4][256][1024]
  float* out = (float*)d_out;                  // [8][512][1024] f32
  char* ws = (char*)d_ws;

  // ws map (temporal reuse, no overlap among concurrently-live buffers):
  //  0-8MB   xn (dead after gemm_qkv) | 8-16MB qb | 16-24MB kb | 24-32MB vt3
  // 32-34MB  wq (dead after gemm_qkv) -> pm/pl (256KB each, live until gemm_out)
  // 34-35MB  wkv | 35-37MB wout | 37MB flag (4B)
  // 38-70MB  mn (dead after gemm_qkv) -> po[0..3] bf16 32MB
  uint16_t* xn   = (uint16_t*)(ws + 0);
  const size_t MB = 1ull << 20;
  uint16_t* qb   = (uint16_t*)(ws + 8*MB);
  uint16_t* kb   = (uint16_t*)(ws + 16*MB);
  uint16_t* vt3  = (uint16_t*)(ws + 24*MB);    // [8][64][4][256][8] bf16 panels
  uint16_t* wq   = (uint16_t*)(ws + 32*MB);
  float*    pm   = (float*)   (ws + 32*MB);                  // 256KB (reuses wq)
  float*    pl   = (float*)   (ws + 32*MB + 262144);         // 256KB
  uint16_t* wkv  = (uint16_t*)(ws + 34*MB);
  uint16_t* wout = (uint16_t*)(ws + 35*MB);
  int*      flag = (int*)     (ws + 37*MB);
  uint16_t* mn   = (uint16_t*)(ws + 38*MB);
  uint16_t* po   = (uint16_t*)(ws + 38*MB);                  // [4][4096][1024] bf16

  hipMemsetAsync(flag, 0, 4, stream);

  fused_pre_k<<<27664, 256, 0, stream>>>(x, mem, xn, mn, rms, qw, kvw, ow,
                                         wq, wkv, wout, (const uint32_t*)mask, flag);

  gemm_qkv_k<<<768, 256, 0, stream>>>(xn, mn, wq, wkv, qb, kb, vt3);

  attn_k<<<256, 512, 0, stream>>>(qb, kb, vt3, mask, flag, po, pm, pl);

  gemm_out_k<<<256, 256, 0, stream>>>(po, pm, pl, wout, out);
}

// Round 23
// 160.676 us; speedup vs baseline: 1.0940x; 1.0940x over previous
//
#include <hip/hip_runtime.h>
#include <stdint.h>

// ---------------- types & helpers ----------------
typedef __bf16   bf16x8 __attribute__((ext_vector_type(8)));
typedef float    f32x4  __attribute__((ext_vector_type(4)));
typedef float    f32x16 __attribute__((ext_vector_type(16)));
typedef uint16_t u16x8  __attribute__((ext_vector_type(8)));
typedef uint16_t u16x4  __attribute__((ext_vector_type(4)));
typedef uint32_t u32x4  __attribute__((ext_vector_type(4)));

#define DEVFN static __device__ __forceinline__

DEVFN uint16_t f2bf(float f){            // RNE f32 -> bf16
  uint32_t u = __builtin_bit_cast(uint32_t, f);
  u += 0x7fffu + ((u >> 16) & 1u);
  return (uint16_t)(u >> 16);
}
DEVFN float bf2f(uint16_t h){
  return __builtin_bit_cast(float, (uint32_t)h << 16);
}
DEVFN bf16x8 ldbf8(const uint16_t* p){
  return __builtin_bit_cast(bf16x8, *(const u16x8*)p);
}
DEVFN void gl16(const void* g, void* l){ // async global->LDS, 16B/lane, LDS base wave-uniform
  __builtin_amdgcn_global_load_lds((__attribute__((address_space(1))) void*)g,
                                   (__attribute__((address_space(3))) void*)l,
                                   16, 0, 0);
}
DEVFN f32x4 mfma16(bf16x8 a, bf16x8 b, f32x4 c){
  return __builtin_amdgcn_mfma_f32_16x16x32_bf16(a, b, c, 0, 0, 0);
}
DEVFN f32x16 mfma32(bf16x8 a, bf16x8 b, f32x16 c){
  return __builtin_amdgcn_mfma_f32_32x32x16_bf16(a, b, c, 0, 0, 0);
}
DEVFN uint32_t cvtpk(float lo, float hi){          // pack 2 f32 -> 2 bf16 in one dword
  uint32_t r;
  asm("v_cvt_pk_bf16_f32 %0, %1, %2" : "=v"(r) : "v"(lo), "v"(hi));
  return r;
}
DEVFN void plswap(uint32_t &x, uint32_t &y){       // swap x.hi-lanes <-> y.lo-lanes
  asm("v_permlane32_swap_b32 %0, %1" : "+v"(x), "+v"(y));
}
// head-local column permutation: rope pair (j, j+128) -> (p, p+16)
DEVFN int permcol(int j){
  return (((j & 127) >> 4) << 5) + (((j >> 7) & 1) << 4) + (j & 15);
}
// fast sincos via HW v_sin/v_cos (input in REVOLUTIONS; fract -> valid domain).
DEVFN void fastsc(float rad, float& sn, float& cs){
  float rev = rad * 0.15915494309189535f;
  rev = __builtin_amdgcn_fractf(rev);
  sn = __builtin_amdgcn_sinf(rev);
  cs = __builtin_amdgcn_cosf(rev);
}

// ---------------- mask dtype detect ----------------
__global__ void detect_mask_k(const uint32_t* m, int* flag){
  int i = blockIdx.x * 256 + threadIdx.x;          // 16 blocks x 256 = 4096 dwords
  uint32_t v = m[i];
  int notint   = (v > 1u) ? 1 : 0;
  int notfloat = (v != 0u && v != 0x3F800000u) ? 2 : 0;
  int bits = notint | notfloat;
  if (__any(bits)){
    int agg = bits;
    agg |= __shfl_xor(agg, 1);  agg |= __shfl_xor(agg, 2);
    agg |= __shfl_xor(agg, 4);  agg |= __shfl_xor(agg, 8);
    agg |= __shfl_xor(agg, 16); agg |= __shfl_xor(agg, 32);
    if ((threadIdx.x & 63) == 0) atomicOr(flag, agg);
  }
}

// ---------------- fused pre-pass: RMSNorm (blocks 0..20479) + weight transpose (rest) ----------------
__global__ __launch_bounds__(256) void fused_pre_k(const float* __restrict__ x,
                                                   const float* __restrict__ mem,
                                                   uint16_t* __restrict__ xn,
                                                   uint16_t* __restrict__ mn,
                                                   const float* __restrict__ scale,
                                                   const float* __restrict__ qw,
                                                   const float* __restrict__ kvw,
                                                   const float* __restrict__ ow,
                                                   uint16_t* __restrict__ wq,
                                                   uint16_t* __restrict__ wkv,
                                                   uint16_t* __restrict__ wout){
  int bid = blockIdx.x;
  if (bid < 20480){
    int row = bid;                 // first 4096 -> x, rest -> mem
    const float* in; uint16_t* out; int r0;
    if (row < 4096){ in = x;  out = xn; r0 = row; }
    else           { in = mem; out = mn; r0 = row - 4096; }
    const float4* ip = (const float4*)(in + (size_t)r0 * 1024);
    float4 v = ip[threadIdx.x];
    float ss = v.x*v.x + v.y*v.y + v.z*v.z + v.w*v.w;
    #pragma unroll
    for (int off = 1; off < 64; off <<= 1) ss += __shfl_xor(ss, off);
    __shared__ float wsum[4];
    if ((threadIdx.x & 63) == 0) wsum[threadIdx.x >> 6] = ss;
    __syncthreads();
    float r = rsqrtf((wsum[0] + wsum[1] + wsum[2] + wsum[3]) * (1.0f/1024.0f) + 1e-6f);
    float4 sc = ((const float4*)scale)[threadIdx.x];
    u16x4 o;
    o[0] = f2bf(v.x * r * (1.0f + sc.x));
    o[1] = f2bf(v.y * r * (1.0f + sc.y));
    o[2] = f2bf(v.z * r * (1.0f + sc.z));
    o[3] = f2bf(v.w * r * (1.0f + sc.w));
    *(u16x4*)(out + (size_t)r0 * 1024 + threadIdx.x * 4) = o;
  } else {
    int t = bid - 20480;           // 7168 = z(7) x y(32) x x(32)
    int z = t >> 10, rem = t & 1023;
    int r0 = (rem >> 5) * 32, c0 = (rem & 31) * 32;
    const float* in; uint16_t* out; int rs, C;
    bool perm;
    if (z < 4)      { in = qw  + z*262144;     out = wq  + z*262144;     rs = 256;  C = 256;  perm = true;  }
    else if (z < 6) { in = kvw + (z-4)*262144; out = wkv + (z-4)*262144; rs = 256;  C = 256;  perm = (z == 4); }
    else            { in = ow;                 out = wout;               rs = 1024; C = 1024; perm = false; }
    if (c0 >= C) return;
    __shared__ float tt[32][33];
    int tx = threadIdx.x & 31, ty = threadIdx.x >> 5;   // (32,8)
    #pragma unroll
    for (int i = 0; i < 4; ++i)
      tt[ty + 8*i][tx] = in[(size_t)(r0 + ty + 8*i) * rs + c0 + tx];
    __syncthreads();
    #pragma unroll
    for (int i = 0; i < 4; ++i){
      int c = c0 + ty + 8*i;
      int pc = perm ? permcol(c) : c;
      out[(size_t)pc * 1024 + r0 + tx] = f2bf(tt[tx][ty + 8*i]);
    }
  }
}

// ---------------- shared GEMM body: BK=64, XOR-swizzled LDS (r18 measured-best) ----------------
#define GEMM_BODY(A_, Bt_, K_)                                                  \
  __shared__ __align__(16) uint16_t As[128*64];                                 \
  __shared__ __align__(16) uint16_t Bs[128*64];                                 \
  f32x4 acc[4][4] = {};                                                         \
  {                                                                             \
    const int K = (K_);                                                         \
    _Pragma("unroll 1")                                                         \
    for (int k0 = 0; k0 < K; k0 += 64){                                         \
      __syncthreads();                                                          \
      _Pragma("unroll")                                                         \
      for (int it = 0; it < 4; ++it){                                           \
        int ob = it * 4096 + tid * 16;                                          \
        int row = ob >> 7;                                                      \
        int col = (ob & 127) ^ ((row & 7) << 4);                                \
        gl16((const char*)(A_)  + ((size_t)(m0 + row) * K + k0) * 2 + col,      \
             (char*)As + it * 4096 + wid * 1024);                               \
        gl16((const char*)(Bt_) + ((size_t)(n0 + row) * K + k0) * 2 + col,      \
             (char*)Bs + it * 4096 + wid * 1024);                               \
      }                                                                         \
      __syncthreads();                                                          \
      bf16x8 af[2][4], bfr[2][4];                                               \
      _Pragma("unroll")                                                         \
      for (int ks = 0; ks < 2; ++ks){                                           \
        _Pragma("unroll")                                                       \
        for (int m = 0; m < 4; ++m)                                             \
          af[ks][m]  = ldbf8(&As[(wr*64 + m*16 + lr) * 64 +                     \
                                 ((ks*32 + lq*8) ^ ((lr & 7) << 3))]);          \
        _Pragma("unroll")                                                       \
        for (int n = 0; n < 4; ++n)                                             \
          bfr[ks][n] = ldbf8(&Bs[(wc*64 + n*16 + lr) * 64 +                     \
                                 ((ks*32 + lq*8) ^ ((lr & 7) << 3))]);          \
      }                                                                         \
      _Pragma("unroll")                                                         \
      for (int ks = 0; ks < 2; ++ks)                                            \
        _Pragma("unroll")                                                       \
        for (int m = 0; m < 4; ++m)                                             \
          _Pragma("unroll")                                                     \
          for (int n = 0; n < 4; ++n)                                           \
            acc[m][n] = mfma16(af[ks][m], bfr[ks][n], acc[m][n]);               \
    }                                                                           \
  }

// ---------------- fused q+kv GEMM; RoPE (HW sin/cos) fused; XCD A-panel affinity ----------------
__global__ __launch_bounds__(256) void gemm_qkv_k(const uint16_t* __restrict__ xn,
                                                  const uint16_t* __restrict__ mn,
                                                  const uint16_t* __restrict__ wq,
                                                  const uint16_t* __restrict__ wkv,
                                                  uint16_t* __restrict__ qb,
                                                  uint16_t* __restrict__ kb,
                                                  uint16_t* __restrict__ vt3){
  int bx = blockIdx.x;
  bool isq = bx < 256;
  const uint16_t *A, *Bt;
  int n0, m0;
  if (isq){
    int m = (bx & 7) + 8 * (bx >> 6);      // XCD = bx%8 = m%8: A-panel pinned to one XCD
    int n = (bx >> 3) & 7;
    A = xn; Bt = wq;  n0 = n * 128;  m0 = m * 128;
  } else {
    int b2 = bx - 256;
    int m = (b2 & 7) + 8 * (b2 >> 5);      // same affinity for kv (256%8==0 preserves xcd)
    int n = (b2 >> 3) & 3;
    A = mn; Bt = wkv; n0 = n * 128; m0 = m * 128;
  }
  int tid = threadIdx.x, lane = tid & 63, wid = tid >> 6;
  int wr = wid >> 1, wc = wid & 1;
  int lr = lane & 15, lq = lane >> 4;
  GEMM_BODY(A, Bt, 1024)
  if (isq){
    // q-block: RoPE fused; v_sin/v_cos path
    #pragma unroll
    for (int m = 0; m < 4; ++m){
      int gr0 = m0 + wr*64 + m*16 + lq*4;
      #pragma unroll
      for (int np = 0; np < 2; ++np){
        int gcl = n0 + wc*64 + (2*np)*16 + lr;         // bit4 == 0: first-half col
        int j = (((gcl & 255) >> 5) << 4) + (gcl & 15);
        float inv = exp2f((float)j * (-13.287712379549449f / 128.0f));
        #pragma unroll
        for (int r = 0; r < 4; ++r){
          float rad = (float)(2048 + ((gr0 + r) & 511)) * inv;
          float sn, cs; fastsc(rad, sn, cs);
          float x1 = acc[m][2*np][r], x2 = acc[m][2*np + 1][r];
          qb[(size_t)(gr0 + r) * 1024 + gcl]      = f2bf((x1*cs - x2*sn) * 0.0625f);
          qb[(size_t)(gr0 + r) * 1024 + gcl + 16] = f2bf((x2*cs + x1*sn) * 0.0625f);
        }
      }
    }
  } else if (n0 < 256){
    // k-block: RoPE fused
    #pragma unroll
    for (int m = 0; m < 4; ++m){
      int gr0 = m0 + wr*64 + m*16 + lq*4;
      #pragma unroll
      for (int np = 0; np < 2; ++np){
        int gcl = n0 + wc*64 + (2*np)*16 + lr;
        int j = ((gcl >> 5) << 4) + (gcl & 15);
        float inv = exp2f((float)j * (-13.287712379549449f / 128.0f));
        #pragma unroll
        for (int r = 0; r < 4; ++r){
          float rad = (float)((gr0 + r) & 2047) * inv;
          float sn, cs; fastsc(rad, sn, cs);
          float x1 = acc[m][2*np][r], x2 = acc[m][2*np + 1][r];
          kb[(size_t)(gr0 + r) * 256 + gcl]      = f2bf(x1*cs - x2*sn);
          kb[(size_t)(gr0 + r) * 256 + gcl + 16] = f2bf(x2*cs + x1*sn);
        }
      }
    }
  } else {
    #pragma unroll
    for (int m = 0; m < 4; ++m)
      #pragma unroll
      for (int n = 0; n < 4; ++n){
        int gr0 = m0 + wr*64 + m*16 + lq*4;
        int gc  = n0 + wc*64 + n*16 + lr;
        int h = gc - 256, bb = gr0 >> 11, s0 = gr0 & 2047;
        int st = s0 >> 5, sc = (s0 >> 3) & 3, s8 = s0 & 7;   // s8 in {0,4}
        u16x4 pk;
        #pragma unroll
        for (int r = 0; r < 4; ++r) pk[r] = f2bf(acc[m][n][r]);
        *(u16x4*)&vt3[((((size_t)bb*64 + st)*4 + sc)*256 + h)*8 + s8] = pk;
      }
  }
}

// ---------------- out GEMM: C[M][N] f32 = A[M][K] * Bt[N][K]^T (XCD A-panel affinity) ----------------
__global__ __launch_bounds__(256) void gemm_out_k(const uint16_t* __restrict__ A,
                                                  const uint16_t* __restrict__ Bt,
                                                  float* __restrict__ Cf){
  int bx = blockIdx.x;                      // 256 blocks, 1-D, XCD-affine like q-part
  int m = (bx & 7) + 8 * (bx >> 6);
  int n = (bx >> 3) & 7;
  int n0 = n * 128, m0 = m * 128;
  int tid = threadIdx.x, lane = tid & 63, wid = tid >> 6;
  int wr = wid >> 1, wc = wid & 1;
  int lr = lane & 15, lq = lane >> 4;
  GEMM_BODY(A, Bt, 1024)
  #pragma unroll
  for (int mm = 0; mm < 4; ++mm)
    #pragma unroll
    for (int nn = 0; nn < 4; ++nn){
      int gr0 = m0 + wr*64 + mm*16 + lq*4;
      int gc  = n0 + wc*64 + nn*16 + lr;
      #pragma unroll
      for (int r = 0; r < 4; ++r) Cf[(size_t)(gr0 + r) * 1024 + gc] = acc[mm][nn][r];
    }
}

// ---------------- flash attention: r14 config + direct-mask prologue (no bias buffer) ----------------
__global__ __launch_bounds__(512, 2) void attn_k(const uint16_t* __restrict__ Q,
                                                 const uint16_t* __restrict__ Kb,
                                                 const uint16_t* __restrict__ Vt3,
                                                 const void* __restrict__ mask,
                                                 const int* __restrict__ flag,
                                                 uint16_t* __restrict__ po,   // [3][4096][1024] bf16
                                                 uint16_t* __restrict__ po3,  // [4096][1024] bf16 (=d_out)
                                                 float* __restrict__ pm,
                                                 float* __restrict__ pl){
  int bx = blockIdx.x;
  int b = bx & 7, qt = (bx >> 3) & 7, sh = bx >> 6;
  int tid = threadIdx.x, lane = tid & 63, wid = tid >> 6;
  int n = wid & 3, qs = wid >> 2;
  int lc = lane & 31, hi = lane >> 5;
  __shared__ __align__(16) uint16_t Ks[3*32*256];   // [buf][s][k], swizzled
  __shared__ __align__(16) uint16_t Vs[3*4*256*8];  // [buf][sc][h][8s] = linear panel copy
  __shared__ uint32_t mask_lds[16];

  int sbeg = sh * 512;
  {
    int f = *flag;                                  // uniform scalar
    int gi = b*2048 + sbeg + tid;
    bool on;
    if ((f & 1) == 0)      on = ((const int*)mask)[gi]    != 0;     // int32
    else if ((f & 2) == 0) on = ((const float*)mask)[gi]  != 0.0f;  // float32
    else                   on = ((const uint8_t*)mask)[gi] != 0;    // bool bytes
    unsigned long long bal = __ballot(on);          // wave wid covers s [wid*64, +64)
    if (lane == 0){
      mask_lds[wid*2]     = (uint32_t)bal;
      mask_lds[wid*2 + 1] = (uint32_t)(bal >> 32);
    }
  }

  int t0w = qt*64 + qs*32;                          // wave's 32 q-rows
  bf16x8 qf[16];
  {
    const uint16_t* qp = Q + (size_t)(b*512 + t0w + lc) * 1024 + n*256 + hi*8;
    #pragma unroll
    for (int kc = 0; kc < 16; ++kc) qf[kc] = ldbf8(qp + kc*16);
  }
  f32x16 o[8] = {};                                 // O[32q][256h]
  float mrow = -1e30f, lrow = 0.0f;

  auto STAGE = [&](int buf, int s0){
    const char* vsrc = (const char*)Vt3 + ((size_t)(b*64 + (s0 >> 5))) * 16384;
    #pragma unroll
    for (int it = 0; it < 2; ++it){
      int ob = it*8192 + tid*16;
      int krow = ob >> 9;                           // K: [32 s][512B], XOR-pre-swizzled source
      int kcol = (ob & 511) ^ ((krow & 7) << 4);
      gl16((const char*)Kb + ((size_t)(b*2048 + s0 + krow) * 256) * 2 + kcol,
           (char*)Ks + buf*16384 + it*8192 + wid*1024);
      gl16(vsrc + ob,                               // V: linear coalesced panel copy
           (char*)Vs + buf*16384 + it*8192 + wid*1024);
    }
  };

  STAGE(0, sbeg);
  STAGE(1, sbeg + 32);

  #pragma unroll 1
  for (int t = 0; t < 16; ++t){
    if (t == 0)      asm volatile("s_waitcnt vmcnt(4) lgkmcnt(0)" ::: "memory");
    else if (t < 15) asm volatile("s_waitcnt vmcnt(4)" ::: "memory");
    else             asm volatile("s_waitcnt vmcnt(0)" ::: "memory");
    __builtin_amdgcn_s_barrier();
    asm volatile("" ::: "memory");
    if (t < 14) STAGE((t+2)%3, sbeg + (t+2)*32);

    const uint16_t* ksb = Ks + (t%3)*8192;
    const uint16_t* vsb = Vs + (t%3)*8192;

    // swapped QK^T: C[s][q], col = q = lc, row s = (reg&3)+8*(reg>>2)+4*hi
    f32x16 sacc = {};
    __builtin_amdgcn_s_setprio(1);
    #pragma unroll
    for (int kc = 0; kc < 16; ++kc){
      bf16x8 ak = ldbf8(&ksb[lc*256 + ((kc*16 + hi*8) ^ ((lc & 7) << 3))]);
      sacc = mfma32(ak, qf[kc], sacc);
    }
    __builtin_amdgcn_s_setprio(0);

    // in-register masked online softmax (lane owns q = lc)
    uint32_t mw = mask_lds[t];
    int sb4 = hi * 4;
    float p[16];
    float mx = -1e30f;
    #pragma unroll
    for (int r = 0; r < 16; ++r){
      int sr = (r & 3) + 8*(r >> 2) + sb4;
      float v = ((mw >> sr) & 1u) ? sacc[r] : -1e30f;
      p[r] = v;
      mx = fmaxf(mx, v);
    }
    mx = fmaxf(mx, __shfl_xor(mx, 32));
    if (__any(mx > mrow + 8.0f)){                   // defer-max (T13)
      float mn2 = fmaxf(mrow, mx);
      float scl = __expf(mrow - mn2);
      mrow = mn2; lrow *= scl;
      #pragma unroll
      for (int ht = 0; ht < 8; ++ht) o[ht] *= scl;
    }
    float rs = 0.0f;
    #pragma unroll
    for (int r = 0; r < 16; ++r){ p[r] = __expf(p[r] - mrow); rs += p[r]; }
    rs += __shfl_xor(rs, 32);
    lrow += rs;

    // P -> bf16 A-frags in registers: cvt_pk pairs + permlane32_swap (T12)
    uint32_t w0, w1, w2, w3, w4, w5, w6, w7;
    w0 = cvtpk(p[0], p[1]);   w2 = cvtpk(p[4], p[5]);   plswap(w0, w2);
    w1 = cvtpk(p[2], p[3]);   w3 = cvtpk(p[6], p[7]);   plswap(w1, w3);
    w4 = cvtpk(p[8], p[9]);   w6 = cvtpk(p[12], p[13]); plswap(w4, w6);
    w5 = cvtpk(p[10], p[11]); w7 = cvtpk(p[14], p[15]); plswap(w5, w7);
    u32x4 t0v = {w0, w1, w2, w3};
    u32x4 t1v = {w4, w5, w6, w7};
    bf16x8 pa0 = __builtin_bit_cast(bf16x8, t0v);   // k = s 0..15
    bf16x8 pa1 = __builtin_bit_cast(bf16x8, t1v);   // k = s 16..31

    // PV: O[q][h], B = V[s][h] from subtiled LDS (conflict-free b128)
    __builtin_amdgcn_s_setprio(1);
    #pragma unroll
    for (int ht = 0; ht < 8; ++ht){
      bf16x8 bv0 = ldbf8(&vsb[(size_t)hi*2048       + (ht*32 + lc)*8]);
      o[ht] = mfma32(pa0, bv0, o[ht]);
      bf16x8 bv1 = ldbf8(&vsb[(size_t)(2 + hi)*2048 + (ht*32 + lc)*8]);
      o[ht] = mfma32(pa1, bv1, o[ht]);
    }
    __builtin_amdgcn_s_setprio(0);
  }

  // epilogue: unscaled partial o (bf16) + per-q m,l
  uint16_t* pop = (sh == 3) ? po3 : po + (size_t)sh * 4194304;
  #pragma unroll
  for (int ht = 0; ht < 8; ++ht)
    #pragma unroll
    for (int r = 0; r < 16; ++r){
      int qr = (r & 3) + 8*(r >> 2) + hi*4;
      pop[(size_t)(b*512 + t0w + qr)*1024 + n*256 + ht*32 + lc] = f2bf(o[ht][r]);
    }
  if (hi == 0){
    int mlidx = sh*16384 + (b*512 + t0w + lc)*4 + n;
    pm[mlidx] = mrow;
    pl[mlidx] = lrow;
  }
}

// ---------------- merge split-S partials (4-way bf16) -> enc bf16 ----------------
__global__ __launch_bounds__(256) void merge_k(const uint16_t* __restrict__ po,
                                               const uint16_t* __restrict__ po3,
                                               const float* __restrict__ pm,
                                               const float* __restrict__ pl,
                                               uint16_t* __restrict__ enc){
  int idx = blockIdx.x * 4 + (threadIdx.x >> 6);   // 16384 = (b*512+t)*4 + n
  int lane = threadIdx.x & 63;
  int row = idx >> 2, n = idx & 3;
  float m = -1e30f;
  #pragma unroll
  for (int h = 0; h < 4; ++h) m = fmaxf(m, pm[h*16384 + idx]);
  float w[4], lsum = 0.0f;
  #pragma unroll
  for (int h = 0; h < 4; ++h){
    w[h] = __expf(pm[h*16384 + idx] - m);
    lsum += pl[h*16384 + idx] * w[h];
  }
  float inv = 1.0f / lsum;
  size_t off = (size_t)row*1024 + n*256 + lane*4;
  float acc[4] = {0.f, 0.f, 0.f, 0.f};
  #pragma unroll
  for (int h = 0; h < 4; ++h){
    const uint16_t* src = (h < 3) ? po + (size_t)h*4194304 + off : po3 + off;
    u16x4 a = *(const u16x4*)src;
    #pragma unroll
    for (int r = 0; r < 4; ++r) acc[r] += bf2f(a[r]) * w[h];
  }
  u16x4 ov;
  #pragma unroll
  for (int r = 0; r < 4; ++r) ov[r] = f2bf(acc[r] * inv);
  *(u16x4*)(enc + off) = ov;
}

// ---------------- launcher ----------------
extern "C" void kernel_launch(void* const* d_in, const int* in_sizes, int n_in,
                              void* d_out, int out_size, void* d_ws, size_t ws_size,
                              hipStream_t stream){
  const float* x    = (const float*)d_in[0];   // [8][512][1024]
  const float* mem  = (const float*)d_in[1];   // [8][2048][1024]
  const void*  mask = d_in[2];                 // [8][2048]
  const float* rms  = (const float*)d_in[3];   // [1024]
  const float* qw   = (const float*)d_in[4];   // [4][1024][256]
  const float* kvw  = (const float*)d_in[5];   // [2][1][1024][256]
  const float* ow   = (const float*)d_in[6];   // [4][256][1024]
  float* out = (float*)d_out;                  // [8][512][1024] f32
  char* ws = (char*)d_ws;

  // ws map (temporal reuse, no overlap among concurrently-live buffers):
  //  0-8MB   xn (dead after gemm_qkv) -> enc | 8-16MB qb | 16-24MB kb | 24-32MB vt3
  // 32-34MB  wq (dead after gemm_qkv) -> pm/pl (256KB each)
  // 34-35MB  wkv | 35-37MB wout | 37MB flag (4B)
  // 38-70MB  mn (dead after gemm_qkv) -> po[0..2] bf16 24MB (38-62MB)
  uint16_t* xn   = (uint16_t*)(ws + 0);
  uint16_t* enc  = (uint16_t*)(ws + 0);
  const size_t MB = 1ull << 20;
  uint16_t* qb   = (uint16_t*)(ws + 8*MB);
  uint16_t* kb   = (uint16_t*)(ws + 16*MB);
  uint16_t* vt3  = (uint16_t*)(ws + 24*MB);    // [8][64][4][256][8] bf16 panels
  uint16_t* wq   = (uint16_t*)(ws + 32*MB);
  float*    pm   = (float*)   (ws + 32*MB);                  // 256KB (reuses wq)
  float*    pl   = (float*)   (ws + 32*MB + 262144);         // 256KB
  uint16_t* wkv  = (uint16_t*)(ws + 34*MB);
  uint16_t* wout = (uint16_t*)(ws + 35*MB);
  int*      flag = (int*)     (ws + 37*MB);
  uint16_t* mn   = (uint16_t*)(ws + 38*MB);
  uint16_t* po   = (uint16_t*)(ws + 38*MB);                  // [3][4096][1024] bf16
  uint16_t* po3  = (uint16_t*)out;                           // 4th partial in d_out

  hipMemsetAsync(flag, 0, 4, stream);
  detect_mask_k<<<16, 256, 0, stream>>>((const uint32_t*)mask, flag);

  fused_pre_k<<<27648, 256, 0, stream>>>(x, mem, xn, mn, rms, qw, kvw, ow, wq, wkv, wout);

  gemm_qkv_k<<<768, 256, 0, stream>>>(xn, mn, wq, wkv, qb, kb, vt3);

  attn_k<<<256, 512, 0, stream>>>(qb, kb, vt3, mask, flag, po, po3, pm, pl);
  merge_k<<<4096, 256, 0, stream>>>(po, po3, pm, pl, enc);

  gemm_out_k<<<256, 256, 0, stream>>>(enc, wout, out);
}